// Round 4
// baseline (448.334 us; speedup 1.0000x reference)
//
#include <hip/hip_runtime.h>

// Problem: B=64, T=2048, D=512, H=64, K=3, S=3, PAD=1
#define T_LEN 2048
#define D_DIM 512
#define B_SZ  64
#define T1_LEN 683     // ceil(2048/3)
#define NSEL  32
#define KTOT  1536     // 3*512 reduction dim of conv1-as-GEMM
#define BK    64       // K chunk per iteration
#define TILE_T1 96     // t1 tile per block; 8 tiles cover 768 >= 683
#define NTILES 8
#define NITER (KTOT / BK)   // 24

typedef __attribute__((ext_vector_type(8))) short bf16x8;
typedef __attribute__((ext_vector_type(4))) float f32x4;

// Workspace layout (bytes)
constexpr size_t OFF_WHI = 0;         // 128*1536 bf16 = 393216 B (pre-swizzled tile layout)
constexpr size_t OFF_WLO = 393216;    // 393216 B
constexpr size_t OFF_EST = 786432;    // 64 floats
constexpr size_t OFF_SEL = 786944;    // 32 ints
constexpr size_t OFF_ZERO = 787072;   // 256 B zero page (16B-aligned)

__device__ inline unsigned bf16_rne(float x) {
    unsigned u = __float_as_uint(x);
    return (u + 0x7FFFu + ((u >> 16) & 1u)) >> 16;
}

// async global->LDS, 16B per lane. LDS dest is wave-uniform base + lane*16;
// we always pass per-thread pointers constructed exactly as base + lane*16.
// The GLOBAL source address is per-lane (swizzle/zero-redirect live there).
__device__ __forceinline__ void gload_lds16(const void* g, void* l) {
    __builtin_amdgcn_global_load_lds(
        (const __attribute__((address_space(1))) unsigned int*)g,
        (__attribute__((address_space(3))) unsigned int*)l,
        16, 0, 0);
}

// ---------------------------------------------------------------------------
// Pack w1[c][d][k] -> whi/wlo in conv1's STAGING layout (pre-swizzled):
//   addr = k0blk*8192 + row*64 + (c8s*8 + e),  where row = c (channel),
//   c8  = c8s ^ (row&7),  kappa = k0blk*64 + c8*8 + e,  kappa = k*512 + d.
// conv1's A-stage is then a contiguous lane-linear copy (global_load_lds)
// and the MFMA-phase read (ch ^ (row&7)) un-swizzles exactly.
// Also zeroes est_raw and the conv1 zero-page (runs before conv1 every launch).
__global__ __launch_bounds__(256) void pack_w1_split(const float* __restrict__ w1,
                                                     unsigned short* __restrict__ whi,
                                                     unsigned short* __restrict__ wlo,
                                                     float* __restrict__ est_raw,
                                                     float* __restrict__ zbuf) {
    if (blockIdx.x == 0 && threadIdx.x < 64) est_raw[threadIdx.x] = 0.f;
    if (blockIdx.x == 0 && threadIdx.x >= 64 && threadIdx.x < 128) zbuf[threadIdx.x - 64] = 0.f;
    int idx = blockIdx.x * 256 + threadIdx.x;   // 768 blocks * 256 = 196608 exact
    int k0blk = idx >> 13;          // /8192
    int rem   = idx & 8191;
    int row   = rem >> 6;           // channel c, 0..127
    int col   = rem & 63;
    int c8s   = col >> 3;
    int e     = col & 7;
    int c8    = c8s ^ (row & 7);
    int kap   = (k0blk << 6) + (c8 << 3) + e;   // k*512 + d
    int k = kap >> 9, d = kap & 511;
    float v = w1[row * 1536 + d * 3 + k];
    unsigned hb = bf16_rne(v);                  // weights: keep full RNE (one-time)
    float hf = __uint_as_float(hb << 16);
    whi[idx] = (unsigned short)hb;
    wlo[idx] = (unsigned short)bf16_rne(v - hf);
}

// ---------------------------------------------------------------------------
// conv1 (GEMM via 3-term split-bf16 MFMA) + bias + pair-maxpool + mod-3
// weighted reduction -> atomicAdd(est_raw[b]).
// Block: batch b, 96-wide t1 tile, all 128 channels. 4 waves, each owns a
// 64c x 48t1 quadrant = 4x3 frags of 16x16 (MFMA 16x16x32 bf16).
// v5: pure-async staging. A staged via global_load_lds from pre-swizzled ws.
// B staged as RAW FP32 via global_load_lds directly from x: source address
// carries the XOR-(row&15) 16B-chunk swizzle (LDS dest must be linear) and
// invalid lanes (t1 tail / left pad) redirect to a zero page. The bf16 hi/lo
// split happens at fragment-read time (off the serial stage path). Stage
// phase = 14 async issues, no VALU, no ds_write, no staging VGPRs.
// Numerics bit-identical to v4 (same trunc split, same MFMA order).
__global__ __launch_bounds__(256, 2) void conv1_mfma(
        const float* __restrict__ x,
        const unsigned short* __restrict__ whi,
        const unsigned short* __restrict__ wlo,
        const float* __restrict__ b1,
        const float* __restrict__ w2,
        float* __restrict__ est_raw,
        const float* __restrict__ zbuf) {
    __shared__ __align__(16) unsigned short Ahi[128 * 64];  // 16 KB
    __shared__ __align__(16) unsigned short Alo[128 * 64];
    __shared__ __align__(16) float Bf[96 * 64];             // 24 KB fp32
    __shared__ float b1s[128];
    __shared__ float w2s[192];
    __shared__ float red[256];

    const int tid  = threadIdx.x;
    const int lane = tid & 63;
    const int w    = tid >> 6;
    const int b    = blockIdx.y;
    const int t1g0 = blockIdx.x * TILE_T1;

    if (tid < 128) b1s[tid] = b1[tid];
    if (tid < 192) w2s[tid] = w2[tid];

    const float* xb = x + (size_t)b * (T_LEN * (size_t)D_DIM);

    const int l15  = lane & 15;
    const int quad = lane >> 4;
    const int c0w  = (w >> 1) * 64;   // c quadrant
    const int t0w  = (w & 1) * 48;    // t1 quadrant

    int offA[4], swA[4];
    #pragma unroll
    for (int mi = 0; mi < 4; ++mi) { int r = c0w + mi * 16 + l15; offA[mi] = r * 64; swA[mi] = r & 7; }
    int rBo[3], jB[3];
    #pragma unroll
    for (int ni = 0; ni < 3; ++ni) { int r = t0w + ni * 16 + l15; rBo[ni] = r * 64; jB[ni] = r & 15; }

    // B staging per-thread constants: 6 slots; slot i covers LDS bytes
    // [w*6144 + i*1024, +1024): this lane owns row = w*24+i*4+(lane>>4),
    // LDS chunk p = lane&15, which must hold GLOBAL chunk c = p ^ (row&15).
    int bbase[6], bthr[6];
    float* bdst[6];
    #pragma unroll
    for (int i = 0; i < 6; ++i) {
        int row   = w * 24 + i * 4 + (lane >> 4);
        int t1abs = t1g0 + row;
        int c     = (lane & 15) ^ (row & 15);
        bbase[i]  = 1536 * t1abs + c * 4 - 512;               // fp32 index + k0
        // valid  <=>  t1abs < 683  &&  bbase + k0 >= 0
        bthr[i]   = (t1abs < T1_LEN) ? (512 - c * 4 - 1536 * t1abs) : 0x7FFFFFFF;
        bdst[i]   = Bf + (w * 1536 + i * 256 + lane * 4);     // = uniform + lane*16B
    }

    f32x4 acc[4][3];
    #pragma unroll
    for (int mi = 0; mi < 4; ++mi)
        #pragma unroll
        for (int ni = 0; ni < 3; ++ni) acc[mi][ni] = (f32x4){0.f, 0.f, 0.f, 0.f};

    for (int it = 0; it < NITER; ++it) {
        const int k0 = it * BK;

        // ---- stage B: 6 async 16B issues, fp32, source-swizzled + zero-page
        #pragma unroll
        for (int i = 0; i < 6; ++i) {
            const float* s = (k0 >= bthr[i]) ? (xb + (bbase[i] + k0)) : zbuf;
            gload_lds16(s, bdst[i]);
        }
        // ---- stage A: 8 async 16B issues from pre-swizzled ws (lane-linear)
        {
            const unsigned short* sH = whi + it * 8192 + tid * 8;
            const unsigned short* sL = wlo + it * 8192 + tid * 8;
            unsigned short* dH = Ahi + tid * 8;
            unsigned short* dL = Alo + tid * 8;
            #pragma unroll
            for (int s = 0; s < 4; ++s) {
                gload_lds16(sH + s * 2048, dH + s * 2048);
                gload_lds16(sL + s * 2048, dL + s * 2048);
            }
        }
        __syncthreads();   // vmcnt(0) drain: A+B tiles visible

        #pragma unroll
        for (int ks = 0; ks < 2; ++ks) {
            const int ch = ks * 4 + quad;
            bf16x8 ah[4], al[4], bh[3], bl[3];
            #pragma unroll
            for (int mi = 0; mi < 4; ++mi) {
                int o = offA[mi] + ((ch ^ swA[mi]) << 3);
                ah[mi] = *(const bf16x8*)(Ahi + o);
                al[mi] = *(const bf16x8*)(Alo + o);
            }
            // B: read 2 swizzled fp32 chunks per fragment, split to hi/lo
            // (trunc-hi perm pack + exact residual; identical math to v4)
            #pragma unroll
            for (int ni = 0; ni < 3; ++ni) {
                int p0 = ((2 * ch)     ^ jB[ni]) << 2;
                int p1 = ((2 * ch + 1) ^ jB[ni]) << 2;
                float4 va = *(const float4*)(Bf + rBo[ni] + p0);   // kappa ch*8..+3
                float4 vb = *(const float4*)(Bf + rBo[ni] + p1);   // kappa ch*8+4..+7
                unsigned f0 = __float_as_uint(va.x), f1 = __float_as_uint(va.y);
                unsigned f2 = __float_as_uint(va.z), f3 = __float_as_uint(va.w);
                unsigned f4 = __float_as_uint(vb.x), f5 = __float_as_uint(vb.y);
                unsigned f6 = __float_as_uint(vb.z), f7 = __float_as_uint(vb.w);
                unsigned hp0 = __builtin_amdgcn_perm(f1, f0, 0x07060302u);
                unsigned hp1 = __builtin_amdgcn_perm(f3, f2, 0x07060302u);
                unsigned hp2 = __builtin_amdgcn_perm(f5, f4, 0x07060302u);
                unsigned hp3 = __builtin_amdgcn_perm(f7, f6, 0x07060302u);
                float r0 = va.x - __uint_as_float(f0 & 0xFFFF0000u);
                float r1 = va.y - __uint_as_float(f1 & 0xFFFF0000u);
                float r2 = va.z - __uint_as_float(f2 & 0xFFFF0000u);
                float r3 = va.w - __uint_as_float(f3 & 0xFFFF0000u);
                float r4 = vb.x - __uint_as_float(f4 & 0xFFFF0000u);
                float r5 = vb.y - __uint_as_float(f5 & 0xFFFF0000u);
                float r6 = vb.z - __uint_as_float(f6 & 0xFFFF0000u);
                float r7 = vb.w - __uint_as_float(f7 & 0xFFFF0000u);
                unsigned lp0 = __builtin_amdgcn_perm(__float_as_uint(r1), __float_as_uint(r0), 0x07060302u);
                unsigned lp1 = __builtin_amdgcn_perm(__float_as_uint(r3), __float_as_uint(r2), 0x07060302u);
                unsigned lp2 = __builtin_amdgcn_perm(__float_as_uint(r5), __float_as_uint(r4), 0x07060302u);
                unsigned lp3 = __builtin_amdgcn_perm(__float_as_uint(r7), __float_as_uint(r6), 0x07060302u);
                int4 hv = make_int4(hp0, hp1, hp2, hp3);
                int4 lv = make_int4(lp0, lp1, lp2, lp3);
                bh[ni] = __builtin_bit_cast(bf16x8, hv);
                bl[ni] = __builtin_bit_cast(bf16x8, lv);
            }
            #pragma unroll
            for (int mi = 0; mi < 4; ++mi)
                #pragma unroll
                for (int ni = 0; ni < 3; ++ni) {
                    acc[mi][ni] = __builtin_amdgcn_mfma_f32_16x16x32_bf16(ah[mi], bh[ni], acc[mi][ni], 0, 0, 0);
                    acc[mi][ni] = __builtin_amdgcn_mfma_f32_16x16x32_bf16(ah[mi], bl[ni], acc[mi][ni], 0, 0, 0);
                    acc[mi][ni] = __builtin_amdgcn_mfma_f32_16x16x32_bf16(al[mi], bh[ni], acc[mi][ni], 0, 0, 0);
                }
        }
        __syncthreads();   // all waves done reading tile t before restage
    }

    // ---- epilogue: bias + pair-maxpool (adjacent regs) + mod-3 w2 weighting
    // est contribution: sum_t2 s[b,t2] = 228*b2 + sum over (j,t1) of
    // hm[j,t1] * w2[j][(t1+1)%3]
    float contrib = 0.f;
    #pragma unroll
    for (int mi = 0; mi < 4; ++mi) {
        const int cbase = c0w + mi * 16 + (quad << 2);   // D row = quad*4 + reg
        const float bb0 = b1s[cbase], bb1 = b1s[cbase + 1];
        const float bb2 = b1s[cbase + 2], bb3 = b1s[cbase + 3];
        const int j0 = cbase >> 1;
        #pragma unroll
        for (int ni = 0; ni < 3; ++ni) {
            const int t1 = t1g0 + t0w + ni * 16 + l15;   // D col = lane&15
            if (t1 < T1_LEN) {
                float p0 = fmaxf(acc[mi][ni][0] + bb0, acc[mi][ni][1] + bb1);
                float p1 = fmaxf(acc[mi][ni][2] + bb2, acc[mi][ni][3] + bb3);
                int r = (t1 + 1) % 3;
                contrib += p0 * w2s[j0 * 3 + r] + p1 * w2s[(j0 + 1) * 3 + r];
            }
        }
    }
    red[tid] = contrib;
    __syncthreads();
    for (int off = 128; off > 0; off >>= 1) {
        if (tid < off) red[tid] += red[tid + off];
        __syncthreads();
    }
    if (tid == 0) atomicAdd(est_raw + b, red[0]);
}

// ---------------------------------------------------------------------------
// Top-32 of 64 (ties -> lower index), ascending compaction; writes sel idx
// and sel_lens (as float, tail of d_out).
__global__ void select_k(const float* __restrict__ est_raw,
                         const float* __restrict__ b2,
                         const int* __restrict__ seq_lens,
                         int* __restrict__ sel,
                         float* __restrict__ out_lens) {
    const int i = threadIdx.x;   // 64 threads = 1 wave
    __shared__ float e[64];
    const int L  = seq_lens[i];
    const int sl = ((L + 2) / 3 + 2) / 3;
    const float ei = (est_raw[i] + 228.0f * b2[0]) / (float)sl;  // = sum/sl
    e[i] = ei;
    __syncthreads();
    int rank = 0;
    for (int j = 0; j < 64; ++j) {
        float ej = e[j];
        rank += (ej > ei) || (ej == ei && j < i);
    }
    const bool selq = rank < NSEL;
    const unsigned long long m = __ballot(selq);
    if (selq) {
        int pos = __popcll(m & ((1ull << i) - 1ull));
        sel[pos] = i;
        out_lens[pos] = (float)L;
    }
}

// ---------------------------------------------------------------------------
__global__ __launch_bounds__(256) void gather_rows(const float* __restrict__ x,
                                                   const int* __restrict__ sel,
                                                   float* __restrict__ out,
                                                   int n4row) {
    const int i = blockIdx.y;
    const int v = blockIdx.x * 256 + threadIdx.x;
    if (v < n4row) {
        const int src = sel[i];
        const float4* xs = (const float4*)(x + (size_t)src * T_LEN * D_DIM);
        float4* od = (float4*)(out + (size_t)i * ((size_t)n4row * 4));
        od[v] = xs[v];
    }
}

// ---------------------------------------------------------------------------
extern "C" void kernel_launch(void* const* d_in, const int* in_sizes, int n_in,
                              void* d_out, int out_size, void* d_ws, size_t ws_size,
                              hipStream_t stream) {
    const float* x        = (const float*)d_in[0];
    const int*   seq_lens = (const int*)  d_in[1];
    const float* w1       = (const float*)d_in[2];
    const float* b1       = (const float*)d_in[3];
    const float* w2       = (const float*)d_in[4];
    const float* b2       = (const float*)d_in[5];
    float* out = (float*)d_out;

    char* ws = (char*)d_ws;
    unsigned short* whi = (unsigned short*)(ws + OFF_WHI);
    unsigned short* wlo = (unsigned short*)(ws + OFF_WLO);
    float* est_raw = (float*)(ws + OFF_EST);
    int*   sel     = (int*)  (ws + OFF_SEL);
    float* zbuf    = (float*)(ws + OFF_ZERO);

    const int max_time = (out_size - NSEL) / (NSEL * D_DIM);

    pack_w1_split<<<768, 256, 0, stream>>>(w1, whi, wlo, est_raw, zbuf);
    conv1_mfma<<<dim3(NTILES, B_SZ), 256, 0, stream>>>(x, whi, wlo, b1, w2, est_raw, zbuf);
    select_k<<<1, 64, 0, stream>>>(est_raw, b2, seq_lens, sel,
                                   out + (size_t)NSEL * max_time * D_DIM);
    const int n4row = max_time * (D_DIM / 4);
    gather_rows<<<dim3((n4row + 255) / 256, NSEL), 256, 0, stream>>>(x, sel, out, n4row);
}

// Round 5
// 444.263 us; speedup vs baseline: 1.0092x; 1.0092x over previous
//
#include <hip/hip_runtime.h>

// Problem: B=64, T=2048, D=512, H=64, K=3, S=3, PAD=1
#define T_LEN 2048
#define D_DIM 512
#define B_SZ  64
#define T1_LEN 683     // ceil(2048/3)
#define NSEL  32
#define KTOT  1536     // 3*512 reduction dim of conv1-as-GEMM
#define BK    32       // K chunk per iteration (double-buffered)
#define TILE_T1 96     // t1 tile per block; 8 tiles cover 768 >= 683
#define NTILES 8
#define NITER (KTOT / BK)   // 48

typedef __attribute__((ext_vector_type(8))) short bf16x8;
typedef __attribute__((ext_vector_type(4))) float f32x4;

// Workspace layout (bytes)
constexpr size_t OFF_WHI = 0;         // 128*1536 bf16 = 393216 B (pre-swizzled BK=32 chunks)
constexpr size_t OFF_WLO = 393216;    // 393216 B
constexpr size_t OFF_EST = 786432;    // 64 floats
constexpr size_t OFF_SEL = 786944;    // 32 ints
constexpr size_t OFF_ZERO = 787072;   // 256 B zero page (16B-aligned)

__device__ inline unsigned bf16_rne(float x) {
    unsigned u = __float_as_uint(x);
    return (u + 0x7FFFu + ((u >> 16) & 1u)) >> 16;
}

// async global->LDS, 16B per lane. LDS dest is wave-uniform base + lane*16;
// all call sites construct dest exactly that way. The GLOBAL source address
// is per-lane (swizzle / zero-page redirect live there).
__device__ __forceinline__ void gload_lds16(const void* g, void* l) {
    __builtin_amdgcn_global_load_lds(
        (const __attribute__((address_space(1))) unsigned int*)g,
        (__attribute__((address_space(3))) unsigned int*)l,
        16, 0, 0);
}

// ---------------------------------------------------------------------------
// Pack w1[c][d][k] -> whi/wlo in conv1's BK=32 STAGING layout (pre-swizzled):
//   addr = k0blk*4096 + row*32 + (c4s*8 + e), row = channel c (0..127),
//   c4  = c4s ^ (row&3),  kappa = k0blk*32 + c4*8 + e,  kappa = k*512 + d.
// conv1's A-stage is a contiguous lane-linear copy (global_load_lds) and the
// MFMA-phase read chunk (ch ^ (row&3)) un-swizzles exactly (bank-uniform).
// Also zeroes est_raw and the conv1 zero-page.
__global__ __launch_bounds__(256) void pack_w1_split(const float* __restrict__ w1,
                                                     unsigned short* __restrict__ whi,
                                                     unsigned short* __restrict__ wlo,
                                                     float* __restrict__ est_raw,
                                                     float* __restrict__ zbuf) {
    if (blockIdx.x == 0 && threadIdx.x < 64) est_raw[threadIdx.x] = 0.f;
    if (blockIdx.x == 0 && threadIdx.x >= 64 && threadIdx.x < 128) zbuf[threadIdx.x - 64] = 0.f;
    int idx = blockIdx.x * 256 + threadIdx.x;   // 768 blocks * 256 = 196608 exact
    int k0blk = idx >> 12;          // /4096 -> chunk 0..47
    int rem   = idx & 4095;
    int row   = rem >> 5;           // channel c, 0..127
    int col   = rem & 31;
    int c4s   = col >> 3;           // LDS chunk slot 0..3
    int e     = col & 7;
    int c4    = c4s ^ (row & 3);    // global chunk held in this slot
    int kap   = (k0blk << 5) + (c4 << 3) + e;   // k*512 + d
    int k = kap >> 9, d = kap & 511;
    float v = w1[row * 1536 + d * 3 + k];
    unsigned hb = bf16_rne(v);                  // weights: keep full RNE (one-time)
    float hf = __uint_as_float(hb << 16);
    whi[idx] = (unsigned short)hb;
    wlo[idx] = (unsigned short)bf16_rne(v - hf);
}

// ---------------------------------------------------------------------------
// conv1 (GEMM via 3-term split-bf16 MFMA) + bias + pair-maxpool + mod-3
// weighted reduction -> atomicAdd(est_raw[b]).
// Block: batch b, 96-wide t1 tile, all 128 channels. 4 waves, each owns a
// 64c x 48t1 quadrant = 4x3 frags of 16x16 (MFMA 16x16x32 bf16).
// v6: depth-1 double-buffered prefetch (T3 minimum 2-phase). Per iter:
//   issue 7 async gload_lds for tile t+1 into the OTHER buffer
//   -> compute tile t (ds_read + read-time split + 36 MFMA)
//   -> one __syncthreads (vmcnt0 drain happens AFTER compute: HBM latency
//      of the prefetch is hidden under the MFMA/VALU phase).
// Staging holds zero registers across compute (gload_lds), so no spill.
// BK=32 keeps the double buffer at the SAME LDS size as v5 (2 blocks/CU).
__global__ __launch_bounds__(256, 2) void conv1_mfma(
        const float* __restrict__ x,
        const unsigned short* __restrict__ whi,
        const unsigned short* __restrict__ wlo,
        const float* __restrict__ b1,
        const float* __restrict__ w2,
        float* __restrict__ est_raw,
        const float* __restrict__ zbuf) {
    __shared__ __align__(16) unsigned short Ahi0[128 * 32];  // 8 KB each
    __shared__ __align__(16) unsigned short Ahi1[128 * 32];
    __shared__ __align__(16) unsigned short Alo0[128 * 32];
    __shared__ __align__(16) unsigned short Alo1[128 * 32];
    __shared__ __align__(16) float Bf0[96 * 32];             // 12 KB each
    __shared__ __align__(16) float Bf1[96 * 32];
    __shared__ float b1s[128];
    __shared__ float w2s[192];
    __shared__ float red[256];

    const int tid  = threadIdx.x;
    const int lane = tid & 63;
    const int w    = tid >> 6;
    const int b    = blockIdx.y;
    const int t1g0 = blockIdx.x * TILE_T1;

    if (tid < 128) b1s[tid] = b1[tid];
    if (tid < 192) w2s[tid] = w2[tid];

    const float* xb = x + (size_t)b * (T_LEN * (size_t)D_DIM);

    const int l15  = lane & 15;
    const int quad = lane >> 4;
    const int c0w  = (w >> 1) * 64;   // c quadrant
    const int t0w  = (w & 1) * 48;    // t1 quadrant

    int offA[4], swA[4];
    #pragma unroll
    for (int mi = 0; mi < 4; ++mi) { int r = c0w + mi * 16 + l15; offA[mi] = r * 32; swA[mi] = r & 3; }
    int rBo[3], jB[3];
    #pragma unroll
    for (int ni = 0; ni < 3; ++ni) { int r = t0w + ni * 16 + l15; rBo[ni] = r * 32; jB[ni] = r & 7; }

    // B staging constants: 3 slots/thread; slot i: id = tid + 256*i,
    // row = id>>3 = (tid>>3)+32*i, LDS chunk p = tid&7 holds GLOBAL chunk
    // c = p ^ (row&7)  (row&7 identical for all 3 slots).
    const int pB   = tid & 7;
    const int rw7  = (tid >> 3) & 7;
    const int cB   = pB ^ rw7;
    int bbase[3], bthr[3], bfo[3];
    #pragma unroll
    for (int i = 0; i < 3; ++i) {
        int row   = (tid >> 3) + 32 * i;
        int t1abs = t1g0 + row;
        bbase[i]  = 1536 * t1abs + cB * 4 - 512;             // fp32 index + k0
        bthr[i]   = (t1abs < T1_LEN) ? (512 - cB * 4 - 1536 * t1abs) : 0x7FFFFFFF;
        bfo[i]    = tid * 4 + 1024 * i;                      // float offset = lane*16B + uniform
    }

    f32x4 acc[4][3];
    #pragma unroll
    for (int mi = 0; mi < 4; ++mi)
        #pragma unroll
        for (int ni = 0; ni < 3; ++ni) acc[mi][ni] = (f32x4){0.f, 0.f, 0.f, 0.f};

    // ---- initial stage into buffer 0 (it = 0)
    {
        #pragma unroll
        for (int i = 0; i < 3; ++i) {
            const float* s = (0 >= bthr[i]) ? (xb + bbase[i]) : zbuf;
            gload_lds16(s, Bf0 + bfo[i]);
        }
        const unsigned short* sH = whi + tid * 8;
        const unsigned short* sL = wlo + tid * 8;
        gload_lds16(sH,        Ahi0 + tid * 8);
        gload_lds16(sH + 2048, Ahi0 + tid * 8 + 2048);
        gload_lds16(sL,        Alo0 + tid * 8);
        gload_lds16(sL + 2048, Alo0 + tid * 8 + 2048);
    }
    __syncthreads();

    #pragma unroll 2
    for (int it = 0; it < NITER; ++it) {
        const int cu = it & 1;
        const unsigned short* AhiC = cu ? Ahi1 : Ahi0;
        const unsigned short* AloC = cu ? Alo1 : Alo0;
        const float*          BfC  = cu ? Bf1  : Bf0;

        // ---- prefetch tile t+1 into the other buffer (7 async issues,
        // zero registers held; latency spans the compute below)
        if (it + 1 < NITER) {
            unsigned short* AhiN = cu ? Ahi0 : Ahi1;
            unsigned short* AloN = cu ? Alo0 : Alo1;
            float*          BfN  = cu ? Bf0  : Bf1;
            const int k0n = (it + 1) * BK;
            #pragma unroll
            for (int i = 0; i < 3; ++i) {
                const float* s = (k0n >= bthr[i]) ? (xb + (bbase[i] + k0n)) : zbuf;
                gload_lds16(s, BfN + bfo[i]);
            }
            const unsigned short* sH = whi + (it + 1) * 4096 + tid * 8;
            const unsigned short* sL = wlo + (it + 1) * 4096 + tid * 8;
            gload_lds16(sH,        AhiN + tid * 8);
            gload_lds16(sH + 2048, AhiN + tid * 8 + 2048);
            gload_lds16(sL,        AloN + tid * 8);
            gload_lds16(sL + 2048, AloN + tid * 8 + 2048);
        }

        // ---- compute tile t from current buffer; ch = quad (4 chunks of 8)
        {
            bf16x8 ah[4], al[4], bh[3], bl[3];
            #pragma unroll
            for (int mi = 0; mi < 4; ++mi) {
                int o = offA[mi] + ((quad ^ swA[mi]) << 3);
                ah[mi] = *(const bf16x8*)(AhiC + o);
                al[mi] = *(const bf16x8*)(AloC + o);
            }
            // B: two swizzled fp32 16B chunks per fragment -> hi/lo split
            // (trunc-hi perm pack + exact residual; identical math to v4/v5)
            #pragma unroll
            for (int ni = 0; ni < 3; ++ni) {
                int p0 = ((2 * quad)     ^ jB[ni]) << 2;
                int p1 = ((2 * quad + 1) ^ jB[ni]) << 2;
                float4 va = *(const float4*)(BfC + rBo[ni] + p0);   // kappa quad*8..+3
                float4 vb = *(const float4*)(BfC + rBo[ni] + p1);   // kappa quad*8+4..+7
                unsigned f0 = __float_as_uint(va.x), f1 = __float_as_uint(va.y);
                unsigned f2 = __float_as_uint(va.z), f3 = __float_as_uint(va.w);
                unsigned f4 = __float_as_uint(vb.x), f5 = __float_as_uint(vb.y);
                unsigned f6 = __float_as_uint(vb.z), f7 = __float_as_uint(vb.w);
                unsigned hp0 = __builtin_amdgcn_perm(f1, f0, 0x07060302u);
                unsigned hp1 = __builtin_amdgcn_perm(f3, f2, 0x07060302u);
                unsigned hp2 = __builtin_amdgcn_perm(f5, f4, 0x07060302u);
                unsigned hp3 = __builtin_amdgcn_perm(f7, f6, 0x07060302u);
                float r0 = va.x - __uint_as_float(f0 & 0xFFFF0000u);
                float r1 = va.y - __uint_as_float(f1 & 0xFFFF0000u);
                float r2 = va.z - __uint_as_float(f2 & 0xFFFF0000u);
                float r3 = va.w - __uint_as_float(f3 & 0xFFFF0000u);
                float r4 = vb.x - __uint_as_float(f4 & 0xFFFF0000u);
                float r5 = vb.y - __uint_as_float(f5 & 0xFFFF0000u);
                float r6 = vb.z - __uint_as_float(f6 & 0xFFFF0000u);
                float r7 = vb.w - __uint_as_float(f7 & 0xFFFF0000u);
                unsigned lp0 = __builtin_amdgcn_perm(__float_as_uint(r1), __float_as_uint(r0), 0x07060302u);
                unsigned lp1 = __builtin_amdgcn_perm(__float_as_uint(r3), __float_as_uint(r2), 0x07060302u);
                unsigned lp2 = __builtin_amdgcn_perm(__float_as_uint(r5), __float_as_uint(r4), 0x07060302u);
                unsigned lp3 = __builtin_amdgcn_perm(__float_as_uint(r7), __float_as_uint(r6), 0x07060302u);
                int4 hv = make_int4(hp0, hp1, hp2, hp3);
                int4 lv = make_int4(lp0, lp1, lp2, lp3);
                bh[ni] = __builtin_bit_cast(bf16x8, hv);
                bl[ni] = __builtin_bit_cast(bf16x8, lv);
            }
            #pragma unroll
            for (int mi = 0; mi < 4; ++mi)
                #pragma unroll
                for (int ni = 0; ni < 3; ++ni) {
                    acc[mi][ni] = __builtin_amdgcn_mfma_f32_16x16x32_bf16(ah[mi], bh[ni], acc[mi][ni], 0, 0, 0);
                    acc[mi][ni] = __builtin_amdgcn_mfma_f32_16x16x32_bf16(ah[mi], bl[ni], acc[mi][ni], 0, 0, 0);
                    acc[mi][ni] = __builtin_amdgcn_mfma_f32_16x16x32_bf16(al[mi], bh[ni], acc[mi][ni], 0, 0, 0);
                }
        }
        // one barrier per iter: drains own prefetch (vmcnt0, already landed
        // under compute) and orders buffer reuse across waves.
        __syncthreads();
    }

    // ---- epilogue: bias + pair-maxpool (adjacent regs) + mod-3 w2 weighting
    // est contribution: sum_t2 s[b,t2] = 228*b2 + sum over (j,t1) of
    // hm[j,t1] * w2[j][(t1+1)%3]
    float contrib = 0.f;
    #pragma unroll
    for (int mi = 0; mi < 4; ++mi) {
        const int cbase = c0w + mi * 16 + (quad << 2);   // D row = quad*4 + reg
        const float bb0 = b1s[cbase], bb1 = b1s[cbase + 1];
        const float bb2 = b1s[cbase + 2], bb3 = b1s[cbase + 3];
        const int j0 = cbase >> 1;
        #pragma unroll
        for (int ni = 0; ni < 3; ++ni) {
            const int t1 = t1g0 + t0w + ni * 16 + l15;   // D col = lane&15
            if (t1 < T1_LEN) {
                float p0 = fmaxf(acc[mi][ni][0] + bb0, acc[mi][ni][1] + bb1);
                float p1 = fmaxf(acc[mi][ni][2] + bb2, acc[mi][ni][3] + bb3);
                int r = (t1 + 1) % 3;
                contrib += p0 * w2s[j0 * 3 + r] + p1 * w2s[(j0 + 1) * 3 + r];
            }
        }
    }
    red[tid] = contrib;
    __syncthreads();
    for (int off = 128; off > 0; off >>= 1) {
        if (tid < off) red[tid] += red[tid + off];
        __syncthreads();
    }
    if (tid == 0) atomicAdd(est_raw + b, red[0]);
}

// ---------------------------------------------------------------------------
// Top-32 of 64 (ties -> lower index), ascending compaction; writes sel idx
// and sel_lens (as float, tail of d_out).
__global__ void select_k(const float* __restrict__ est_raw,
                         const float* __restrict__ b2,
                         const int* __restrict__ seq_lens,
                         int* __restrict__ sel,
                         float* __restrict__ out_lens) {
    const int i = threadIdx.x;   // 64 threads = 1 wave
    __shared__ float e[64];
    const int L  = seq_lens[i];
    const int sl = ((L + 2) / 3 + 2) / 3;
    const float ei = (est_raw[i] + 228.0f * b2[0]) / (float)sl;  // = sum/sl
    e[i] = ei;
    __syncthreads();
    int rank = 0;
    for (int j = 0; j < 64; ++j) {
        float ej = e[j];
        rank += (ej > ei) || (ej == ei && j < i);
    }
    const bool selq = rank < NSEL;
    const unsigned long long m = __ballot(selq);
    if (selq) {
        int pos = __popcll(m & ((1ull << i) - 1ull));
        sel[pos] = i;
        out_lens[pos] = (float)L;
    }
}

// ---------------------------------------------------------------------------
__global__ __launch_bounds__(256) void gather_rows(const float* __restrict__ x,
                                                   const int* __restrict__ sel,
                                                   float* __restrict__ out,
                                                   int n4row) {
    const int i = blockIdx.y;
    const int v = blockIdx.x * 256 + threadIdx.x;
    if (v < n4row) {
        const int src = sel[i];
        const float4* xs = (const float4*)(x + (size_t)src * T_LEN * D_DIM);
        float4* od = (float4*)(out + (size_t)i * ((size_t)n4row * 4));
        od[v] = xs[v];
    }
}

// ---------------------------------------------------------------------------
extern "C" void kernel_launch(void* const* d_in, const int* in_sizes, int n_in,
                              void* d_out, int out_size, void* d_ws, size_t ws_size,
                              hipStream_t stream) {
    const float* x        = (const float*)d_in[0];
    const int*   seq_lens = (const int*)  d_in[1];
    const float* w1       = (const float*)d_in[2];
    const float* b1       = (const float*)d_in[3];
    const float* w2       = (const float*)d_in[4];
    const float* b2       = (const float*)d_in[5];
    float* out = (float*)d_out;

    char* ws = (char*)d_ws;
    unsigned short* whi = (unsigned short*)(ws + OFF_WHI);
    unsigned short* wlo = (unsigned short*)(ws + OFF_WLO);
    float* est_raw = (float*)(ws + OFF_EST);
    int*   sel     = (int*)  (ws + OFF_SEL);
    float* zbuf    = (float*)(ws + OFF_ZERO);

    const int max_time = (out_size - NSEL) / (NSEL * D_DIM);

    pack_w1_split<<<768, 256, 0, stream>>>(w1, whi, wlo, est_raw, zbuf);
    conv1_mfma<<<dim3(NTILES, B_SZ), 256, 0, stream>>>(x, whi, wlo, b1, w2, est_raw, zbuf);
    select_k<<<1, 64, 0, stream>>>(est_raw, b2, seq_lens, sel,
                                   out + (size_t)NSEL * max_time * D_DIM);
    const int n4row = max_time * (D_DIM / 4);
    gather_rows<<<dim3((n4row + 255) / 256, NSEL), 256, 0, stream>>>(x, sel, out, n4row);
}